// Round 5
// baseline (18724.661 us; speedup 1.0000x reference)
//
#include <hip/hip_runtime.h>

#define BB 64
#define NN 1000
#define FF 12
#define EE 64
#define HH 128
#define OO 16

__device__ __forceinline__ float rcp_(float x){ return __builtin_amdgcn_rcpf(x); }
__device__ __forceinline__ float sigm_(float x){ return rcp_(1.0f + __expf(-x)); }
// exact algebraic tanh: 1 - 2/(e^{2x}+1)
__device__ __forceinline__ float tanh_(float x){ return 1.0f - 2.0f*rcp_(__expf(2.0f*x) + 1.0f); }

__device__ __forceinline__ float4 fma4(float4 a, float4 x, float4 w){
    a.x += x.x*w.x; a.y += x.y*w.y; a.z += x.z*w.z; a.w += x.w*w.w; return a;
}
__device__ __forceinline__ float hsum4(float4 a){ return (a.x+a.y)+(a.z+a.w); }

// V5: 256 threads (4 waves). TWO barriers per step (cross-wave hfull exchange
// only). Projection is per-wave redundant; h1/h2 broadcast through wave-private
// LDS slots (intra-wave RAW -> lgkmcnt only, no barrier). Pair trick (R4): lane
// pair (2u,2u+1) owns unit u, gates never cross waves. All global traffic
// (enc/mean loads, Wih0 enc-row streams, out flush) confined to node boundary
// so the 24 f-loop barriers see no outstanding vmem.
__global__ __launch_bounds__(256, 1)
void decoder_kernel(const float* __restrict__ enc,   // (B,1,N,E)
                    const float* __restrict__ mean,  // (B,FUT,N,O)
                    const float* __restrict__ sv,    // (1,O)
                    const float* __restrict__ h0,    // (2,O)
                    const float* __restrict__ c0,    // (2,H)
                    const float* __restrict__ Wih0,  // (4H, E+O)
                    const float* __restrict__ Whh0,  // (4H, O)
                    const float* __restrict__ bih0,  // (4H)
                    const float* __restrict__ bhh0,  // (4H)
                    const float* __restrict__ Whr0,  // (O, H)
                    const float* __restrict__ Wih1,  // (4H, O)
                    const float* __restrict__ Whh1,  // (4H, O)
                    const float* __restrict__ bih1,  // (4H)
                    const float* __restrict__ bhh1,  // (4H)
                    const float* __restrict__ Whr1,  // (O, H)
                    float* __restrict__ out)         // (B,FUT,N,O)
{
    const int t  = threadIdx.x;
    const int b  = blockIdx.x;
    const int wv = t >> 6;
    const int lane = t & 63;

    const int u  = t >> 1;            // unit 0..127 (pair within a wave)
    const int m  = t & 1;             // 0: i,g   1: f,o
    const int rA = m*HH + u;
    const int rB = rA + 2*HH;

    const int j = lane >> 2;          // proj output 0..15 (per wave)
    const int q = lane & 3;           // proj K-chunk q*32..q*32+31
    const int hfpad = u + ((u>>5)<<2);

    __shared__ __align__(16) float s_hf1[4*36];
    __shared__ __align__(16) float s_hf2[4*36];
    __shared__ __align__(16) float s_hw1[4][OO];   // wave-private h1
    __shared__ __align__(16) float s_hw2[4][OO];   // wave-private h2
    __shared__ __align__(16) float s_enc[EE];
    __shared__ __align__(16) float s_nm[OO];
    __shared__ __align__(16) float s_out[FF*OO];
    __shared__ __align__(16) float s_bh2[OO];      // boot h2 = h_0[1]

    // ---- recurrent weights in registers ----
    float4 wAl[4], wBl[4], wAh[4], wBh[4];
    float4 w1Ai[4], w1Bi[4], w1Ah[4], w1Bh[4];
    #pragma unroll
    for (int k=0;k<4;k++){
        wAl[k]  = *(const float4*)&Wih0[(size_t)rA*(EE+OO) + EE + 4*k];
        wBl[k]  = *(const float4*)&Wih0[(size_t)rB*(EE+OO) + EE + 4*k];
        wAh[k]  = *(const float4*)&Whh0[rA*OO + 4*k];
        wBh[k]  = *(const float4*)&Whh0[rB*OO + 4*k];
        w1Ai[k] = *(const float4*)&Wih1[rA*OO + 4*k];
        w1Bi[k] = *(const float4*)&Wih1[rB*OO + 4*k];
        w1Ah[k] = *(const float4*)&Whh1[rA*OO + 4*k];
        w1Bh[k] = *(const float4*)&Whh1[rB*OO + 4*k];
    }
    const float b0A = bih0[rA] + bhh0[rA];
    const float b0B = bih0[rB] + bhh0[rB];
    const float b1A = bih1[rA] + bhh1[rA];
    const float b1B = bih1[rB] + bhh1[rB];

    float4 wp0[8], wp1[8];
    #pragma unroll
    for (int i=0;i<8;i++){
        wp0[i] = *(const float4*)&Whr0[j*HH + q*32 + 4*i];
        wp1[i] = *(const float4*)&Whr1[j*HH + q*32 + 4*i];
    }

    float c1u = c0[u];
    float c2u = c0[HH + u];

    // h-state register vectors (all threads): h2v doubles as 'last'
    float4 h1v[4], h2v[4];
    #pragma unroll
    for (int k=0;k<4;k++){
        h1v[k] = *(const float4*)&h0[4*k];       // h_0[0]
        h2v[k] = *(const float4*)&sv[4*k];       // last0 = s[0]
    }
    if (t < OO) s_bh2[t] = h0[OO + t];           // true initial h2 = h_0[1]

    const float* encB  = enc  + (size_t)b * NN * EE;
    const float* meanB = mean + (size_t)b * FF * NN * OO;
    float*       outB  = out  + (size_t)b * FF * NN * OO;

    const float4* wrowA = (const float4*)(Wih0 + (size_t)rA*(EE+OO));
    const float4* wrowB = (const float4*)(Wih0 + (size_t)rB*(EE+OO));

    float preA = 0.f, preB = 0.f, nmj = 0.f;

    // layer-0 gates+cell (writes s_hf1); layer-1 gates+cell (writes s_hf2)
    auto gates0 = [&](){
        float4 accA = make_float4(preA,0.f,0.f,0.f);
        float4 accB = make_float4(preB,0.f,0.f,0.f);
        #pragma unroll
        for (int k=0;k<4;k++){
            accA = fma4(accA, h2v[k], wAl[k]); accA = fma4(accA, h1v[k], wAh[k]);
            accB = fma4(accB, h2v[k], wBl[k]); accB = fma4(accB, h1v[k], wBh[k]);
        }
        const float aA = hsum4(accA), aB = hsum4(accB);
        const float gA = sigm_(aA);
        const float gB = (m==0) ? tanh_(aB) : sigm_(aB);
        const float sendv = (m==0) ? gA*gB : gA;
        const float recvv = __shfl_xor(sendv, 1, 64);
        const float Fv    = (m==0) ? recvv : sendv;
        const float prod  = (m==0) ? sendv : recvv;
        c1u = Fv*c1u + prod;
        if (m) s_hf1[hfpad] = gB * tanh_(c1u);
    };
    auto gates1 = [&](){
        float4 accA = make_float4(b1A,0.f,0.f,0.f);
        float4 accB = make_float4(b1B,0.f,0.f,0.f);
        #pragma unroll
        for (int k=0;k<4;k++){
            accA = fma4(accA, h1v[k], w1Ai[k]); accA = fma4(accA, h2v[k], w1Ah[k]);
            accB = fma4(accB, h1v[k], w1Bi[k]); accB = fma4(accB, h2v[k], w1Bh[k]);
        }
        const float aA = hsum4(accA), aB = hsum4(accB);
        const float gA = sigm_(aA);
        const float gB = (m==0) ? tanh_(aB) : sigm_(aB);
        const float sendv = (m==0) ? gA*gB : gA;
        const float recvv = __shfl_xor(sendv, 1, 64);
        const float Fv    = (m==0) ? recvv : sendv;
        const float prod  = (m==0) ? sendv : recvv;
        c2u = Fv*c2u + prod;
        if (m) s_hf2[hfpad] = gB * tanh_(c2u);
    };

    for (int n = 0; n < NN; ++n){
        // ---- node boundary: flush prev outputs, load enc/nm ----
        if (n > 0 && t < 48){
            const int ff = t >> 2, o4 = (t & 3) * 4;
            *(float4*)&outB[(size_t)(ff*NN + (n-1))*OO + o4] =
                *(const float4*)&s_out[ff*OO + o4];
        }
        if (t < 16){
            ((float4*)s_enc)[t] = ((const float4*)(encB + (size_t)n*EE))[t];
        } else if (t >= 64 && t < 80){
            const int jj = t - 64;
            float a = 0.0f;
            #pragma unroll
            for (int ff=0; ff<FF; ++ff) a += meanB[(size_t)(ff*NN + n)*OO + jj];
            s_nm[jj] = a * (1.0f/12.0f);
        }
        __syncthreads();                                   // bar: commit enc/nm

        // pre0 = bias + enc·W (streamed, L2-resident) + nm·w_loop
        {
            float4 sa = make_float4(b0A,0.f,0.f,0.f);
            float4 sb = make_float4(b0B,0.f,0.f,0.f);
            #pragma unroll
            for (int k=0;k<16;k++){
                const float4 e = ((const float4*)s_enc)[k];
                sa = fma4(sa, e, wrowA[k]);
                sb = fma4(sb, e, wrowB[k]);
            }
            #pragma unroll
            for (int k=0;k<4;k++){
                const float4 nm4 = ((const float4*)s_nm)[k];
                sa = fma4(sa, nm4, wAl[k]); sb = fma4(sb, nm4, wBl[k]);
            }
            preA = hsum4(sa); preB = hsum4(sb);
        }
        nmj = s_nm[j];

        // gates0 for f=0 (h2v = last, h1v = h1)
        gates0();
        __syncthreads();                                   // bar: s_hf1 ready

        #pragma unroll 1
        for (int f = 0; f < FF; ++f){
            // ---- Phase A: proj0 -> h1 (wave-private) -> gates1+cell1 ----
            {
                float4 acc = make_float4(0.f,0.f,0.f,0.f);
                #pragma unroll
                for (int i=0;i<8;i++)
                    acc = fma4(acc, *(const float4*)&s_hf1[q*36 + 4*i], wp0[i]);
                float p = hsum4(acc);
                p += __shfl_xor(p, 1, 64);
                p += __shfl_xor(p, 2, 64);
                if (q == 0) s_hw1[wv][j] = p;
                if (n == 0 && f == 0){
                    #pragma unroll
                    for (int k=0;k<4;k++) h2v[k] = ((const float4*)s_bh2)[k];
                }
                #pragma unroll
                for (int k=0;k<4;k++) h1v[k] = ((const float4*)&s_hw1[wv][0])[k];
                gates1();
            }
            __syncthreads();                               // BAR A (s_hf2)

            // ---- Phase B: proj1 -> h2/last + out -> gates0(next) ----
            {
                float4 acc = make_float4(0.f,0.f,0.f,0.f);
                #pragma unroll
                for (int i=0;i<8;i++)
                    acc = fma4(acc, *(const float4*)&s_hf2[q*36 + 4*i], wp1[i]);
                float p = hsum4(acc);
                p += __shfl_xor(p, 1, 64);
                p += __shfl_xor(p, 2, 64);
                if (q == 0){
                    s_hw2[wv][j] = p;
                    if (wv == 0) s_out[f*OO + j] = p + nmj;
                }
                #pragma unroll
                for (int k=0;k<4;k++) h2v[k] = ((const float4*)&s_hw2[wv][0])[k];
                if (f < FF-1) gates0();
            }
            __syncthreads();                               // BAR B (s_hf1)
        }
    }

    // flush final node's outputs
    if (t < 48){
        const int ff = t >> 2, o4 = (t & 3) * 4;
        *(float4*)&outB[(size_t)(ff*NN + (NN-1))*OO + o4] =
            *(const float4*)&s_out[ff*OO + o4];
    }
}

extern "C" void kernel_launch(void* const* d_in, const int* in_sizes, int n_in,
                              void* d_out, int out_size, void* d_ws, size_t ws_size,
                              hipStream_t stream) {
    const float* enc  = (const float*)d_in[0];
    const float* mean = (const float*)d_in[1];
    const float* sv   = (const float*)d_in[2];
    const float* h0   = (const float*)d_in[3];
    const float* c0   = (const float*)d_in[4];
    const float* Wih0 = (const float*)d_in[5];
    const float* Whh0 = (const float*)d_in[6];
    const float* bih0 = (const float*)d_in[7];
    const float* bhh0 = (const float*)d_in[8];
    const float* Whr0 = (const float*)d_in[9];
    const float* Wih1 = (const float*)d_in[10];
    const float* Whh1 = (const float*)d_in[11];
    const float* bih1 = (const float*)d_in[12];
    const float* bhh1 = (const float*)d_in[13];
    const float* Whr1 = (const float*)d_in[14];
    float* out = (float*)d_out;

    decoder_kernel<<<dim3(BB), dim3(256), 0, stream>>>(
        enc, mean, sv, h0, c0,
        Wih0, Whh0, bih0, bhh0, Whr0,
        Wih1, Whh1, bih1, bhh1, Whr1,
        out);
}